// Round 1
// 205.029 us; speedup vs baseline: 1.0017x; 1.0017x over previous
//
#include <hip/hip_runtime.h>

// SENet layer, fp32 NHWC. B=32, H=W=56 (HW=3136), C=256, C/R=16.
//  A:  partial spatial sums -> ws partial [B*49][256] fp32
//  B1: per-batch: reduce 49 partials + MLP -> g [32][256] fp32 (tiny, once)
//  B2: pure streaming scale: out = x * g. No LDS, no barriers, no prologue.

#define BATCH 32
#define HW 3136
#define C 256
#define CR 16
#define SBLK 49            // spatial blocks per batch (3136/64 rows)
#define VPR 64             // float4 vectors per row (256 floats / 4)

typedef float v4f __attribute__((ext_vector_type(4)));

// ---------------- kernel A: partial pooling sums ----------------
__global__ __launch_bounds__(256) void se_pool_partial(
        const float* __restrict__ x, float* __restrict__ partial) {
    const int b    = blockIdx.x / SBLK;
    const int sblk = blockIdx.x % SBLK;
    const int tid  = threadIdx.x;
    const int lane = tid & 63;   // float4 index within a row (0..63)
    const int rg   = tid >> 6;   // row group (0..3)

    const v4f* __restrict__ xv = (const v4f*)x;
    const int row0 = sblk * 64;

    v4f a = (v4f)(0.f);
#pragma unroll
    for (int k = 0; k < 16; ++k) {
        const int r = row0 + rg + 4 * k;
        a += xv[(size_t)(b * HW + r) * VPR + lane];
    }

    __shared__ float red[256 * 4];
    red[tid * 4 + 0] = a.x;
    red[tid * 4 + 1] = a.y;
    red[tid * 4 + 2] = a.z;
    red[tid * 4 + 3] = a.w;
    __syncthreads();

    if (tid < 64) {
#pragma unroll
        for (int gg = 1; gg < 4; ++gg) {
            a.x += red[(gg * 64 + tid) * 4 + 0];
            a.y += red[(gg * 64 + tid) * 4 + 1];
            a.z += red[(gg * 64 + tid) * 4 + 2];
            a.w += red[(gg * 64 + tid) * 4 + 3];
        }
        float* dst = partial + (size_t)(b * SBLK + sblk) * C + tid * 4;
        dst[0] = a.x; dst[1] = a.y; dst[2] = a.z; dst[3] = a.w;
    }
}

// ---------------- kernel B1: reduce partials + MLP -> g (once per batch) ---
__global__ __launch_bounds__(256) void se_mlp(
        const float* __restrict__ partial,
        const float* __restrict__ w1, const float* __restrict__ b1,
        const float* __restrict__ w2, const float* __restrict__ b2,
        float* __restrict__ g) {
    const int b   = blockIdx.x;
    const int tid = threadIdx.x;

    __shared__ float s[C];
    __shared__ float red[C];
    __shared__ float h[CR];

    // pooled mean for batch b (49 partials)
    {
        float sum = 0.f;
        const float* pb = partial + (size_t)b * SBLK * C + tid;
#pragma unroll 7
        for (int k = 0; k < SBLK; ++k) sum += pb[k * C];
        s[tid] = sum * (1.0f / (float)HW);
    }
    __syncthreads();

    // layer 1: h = relu(s @ w1 + b1).  16 outputs x 16 reduction lanes.
    {
        const int j = tid & 15;
        const int i = tid >> 4;
        float a = 0.f;
#pragma unroll
        for (int t = 0; t < 16; ++t) {
            const int k = t * 16 + i;
            a += s[k] * w1[k * CR + j];
        }
        red[tid] = a;
    }
    __syncthreads();
    if (tid < CR) {
        float acc = b1[tid];
#pragma unroll
        for (int i2 = 0; i2 < 16; ++i2) acc += red[i2 * 16 + tid];
        h[tid] = fmaxf(acc, 0.f);
    }
    __syncthreads();

    // layer 2: g = sigmoid(h @ w2 + b2), one channel per thread, coalesced w2.
    {
        float acc = b2[tid];
#pragma unroll
        for (int t = 0; t < CR; ++t) acc += h[t] * w2[t * C + tid];
        g[(size_t)b * C + tid] = 1.f / (1.f + expf(-acc));
    }
}

// ---------------- kernel B2: pure streaming scale --------------------------
__global__ __launch_bounds__(256) void se_scale(
        const float* __restrict__ x, const float* __restrict__ g,
        float* __restrict__ out) {
    const int b    = blockIdx.x / SBLK;
    const int sblk = blockIdx.x % SBLK;
    const int tid  = threadIdx.x;

    // gate for this thread's channel quad: one coalesced float4 load, L2-hit.
    const v4f gv = ((const v4f*)g)[b * VPR + (tid & 63)];

    // float4 vectors: per batch = HW*VPR = 200704; per block = 4096; per thread = 16
    const size_t base = (size_t)b * (HW * VPR) + (size_t)sblk * 4096;
    const v4f* __restrict__ xv = (const v4f*)x;
    v4f* __restrict__ ov = (v4f*)out;

#pragma unroll
    for (int k = 0; k < 16; ++k) {
        const size_t p = base + tid + (size_t)k * 256;
        v4f v = __builtin_nontemporal_load(&xv[p]);   // last use of x
        v.x *= gv.x; v.y *= gv.y; v.z *= gv.z; v.w *= gv.w;
        __builtin_nontemporal_store(v, &ov[p]);       // never re-read
    }
}

extern "C" void kernel_launch(void* const* d_in, const int* in_sizes, int n_in,
                              void* d_out, int out_size, void* d_ws, size_t ws_size,
                              hipStream_t stream) {
    const float* x  = (const float*)d_in[0];
    const float* w1 = (const float*)d_in[1];
    const float* b1 = (const float*)d_in[2];
    const float* w2 = (const float*)d_in[3];
    const float* b2 = (const float*)d_in[4];
    float* out = (float*)d_out;

    float* partial = (float*)d_ws;                       // B*SBLK*C floats = 1.6 MB
    float* g       = partial + (size_t)BATCH * SBLK * C; // +32 KB, 16B-aligned

    se_pool_partial<<<dim3(BATCH * SBLK), dim3(256), 0, stream>>>(x, partial);
    se_mlp<<<dim3(BATCH), dim3(256), 0, stream>>>(partial, w1, b1, w2, b2, g);
    se_scale<<<dim3(BATCH * SBLK), dim3(256), 0, stream>>>(x, g, out);
}